// Round 3
// baseline (22936.110 us; speedup 1.0000x reference)
//
#include <hip/hip_runtime.h>

#define T_TOTAL 8000
#define UDIM 512
#define NG 2048
#define GWG 32   // workgroups per pass
#define NUW 16   // LSTM units per workgroup

typedef unsigned long long ull;

__device__ __forceinline__ float sig_f(float x) { return 1.f / (1.f + __expf(-x)); }
__device__ __forceinline__ float tanh_f(float x) { return 1.f - 2.f / (__expf(2.f * x) + 1.f); }

// ---------------- init: unpack states into epoch-tagged pairs ----------------
// pair layout: low32 = epoch, high32 = float bits of h.
// buffer0 gets (h0, epoch=0) -- consumers at t=0 require epoch==0.
// buffer1 gets sentinel epoch 0xDEADBEEF (must clear: ws poisoned).
__global__ void init_kernel(const float* __restrict__ st, ull* hp, float* cs) {
  int idx = blockIdx.x * blockDim.x + threadIdx.x;
  if (idx < 2048) {  // p*512+u
    unsigned hb = __float_as_uint(st[2 * idx + 0]);
    hp[idx]        = ((ull)hb << 32) | 0ull;
    hp[2048 + idx] = 0xDEADBEEFull;
    cs[idx] = st[2 * idx + 1];
  }
}

// ---------------- projection: xz[p][t][2048] = x_p @ W_p + b_p ----------------
__global__ __launch_bounds__(256) void proj_kernel(
    const float* __restrict__ in_real, const float* __restrict__ in_imag,
    const float* __restrict__ Wr, const float* __restrict__ br,
    const float* __restrict__ Wi, const float* __restrict__ bi,
    float* __restrict__ xz, int t0, int chunk) {
  const int p = blockIdx.z;
  const float* __restrict__ X = (p < 2) ? in_real : in_imag;
  const float* __restrict__ W = (p & 1) ? Wi : Wr;
  const float* __restrict__ Bv = (p & 1) ? bi : br;
  const int nb = blockIdx.x * 64, mb = blockIdx.y * 64;
  __shared__ float As[16][68];
  __shared__ float Bs[16][68];
  const int tid = threadIdx.x;
  const int tm = tid >> 4, tn = tid & 15;
  const int lam = tid >> 2, lak = (tid & 3) << 2;   // A: row, k-offset
  const int lbk = tid >> 4, lbn = (tid & 15) << 2;  // B: k, col-offset
  float acc[4][4] = {};
  for (int k0 = 0; k0 < 512; k0 += 16) {
    int msafe = mb + lam; if (msafe > chunk - 1) msafe = chunk - 1;
    float4 a4 = *(const float4*)&X[(size_t)(t0 + msafe) * 512 + k0 + lak];
    float4 b4 = *(const float4*)&W[(size_t)(k0 + lbk) * 2048 + nb + lbn];
    __syncthreads();
    As[lak + 0][lam] = a4.x; As[lak + 1][lam] = a4.y;
    As[lak + 2][lam] = a4.z; As[lak + 3][lam] = a4.w;
    *(float4*)&Bs[lbk][lbn] = b4;
    __syncthreads();
#pragma unroll
    for (int k = 0; k < 16; ++k) {
      float4 av = *(const float4*)&As[k][tm << 2];
      float4 bv = *(const float4*)&Bs[k][tn << 2];
      acc[0][0] = fmaf(av.x, bv.x, acc[0][0]); acc[0][1] = fmaf(av.x, bv.y, acc[0][1]);
      acc[0][2] = fmaf(av.x, bv.z, acc[0][2]); acc[0][3] = fmaf(av.x, bv.w, acc[0][3]);
      acc[1][0] = fmaf(av.y, bv.x, acc[1][0]); acc[1][1] = fmaf(av.y, bv.y, acc[1][1]);
      acc[1][2] = fmaf(av.y, bv.z, acc[1][2]); acc[1][3] = fmaf(av.y, bv.w, acc[1][3]);
      acc[2][0] = fmaf(av.z, bv.x, acc[2][0]); acc[2][1] = fmaf(av.z, bv.y, acc[2][1]);
      acc[2][2] = fmaf(av.z, bv.z, acc[2][2]); acc[2][3] = fmaf(av.z, bv.w, acc[2][3]);
      acc[3][0] = fmaf(av.w, bv.x, acc[3][0]); acc[3][1] = fmaf(av.w, bv.y, acc[3][1]);
      acc[3][2] = fmaf(av.w, bv.z, acc[3][2]); acc[3][3] = fmaf(av.w, bv.w, acc[3][3]);
    }
  }
  float4 bias4 = *(const float4*)&Bv[nb + (tn << 2)];
#pragma unroll
  for (int i = 0; i < 4; ++i) {
    int mm = mb + (tm << 2) + i;
    if (mm < chunk) {
      float4 v;
      v.x = acc[i][0] + bias4.x; v.y = acc[i][1] + bias4.y;
      v.z = acc[i][2] + bias4.z; v.w = acc[i][3] + bias4.w;
      *(float4*)&xz[(size_t)(p * chunk + mm) * 2048 + nb + (tn << 2)] = v;
    }
  }
}

// ---------------- persistent recurrent kernel ----------------
// grid = 128 blocks, 256 threads. block: pass p = bx&3, slice g = bx>>2.
// thread (wave w, lane l): k-range = w*128 + (l>>4)*32 .. +32, unit uu = l&15;
// holds R[k][uu + 512*gate] for 4 gates in 128 regs.
// Exchange: epoch-tagged 8B pairs (low=epoch, high=h bits), agent-scope relaxed
// atomics. ONE coherence round trip per step: the data loads ARE the poll
// (validate epoch==t on the loaded registers, GEMV consumes those registers).
// Producer side is a single fire-and-forget 8B store -- no vmcnt ack, no flag.
// Safety: a producer can write epoch t+2 into buffer t&1 only after ALL WGs
// published t+1, which requires them to have register-captured epoch-t data.
// Per-thread polling removes the pre-GEMV barrier; zpart[2] double-buffer
// removes the post-read barrier -> exactly 1 __syncthreads per step.
__global__ __launch_bounds__(256, 1) void recur_kernel(
    const float* __restrict__ xz, const float* __restrict__ Rr, const float* __restrict__ Ri,
    ull* hp, float* cs, float* out, int t0, int chunk) {
  const int tid = threadIdx.x;
  const int w = tid >> 6, l = tid & 63;
  const int uu = l & 15, kg = l >> 4;
  const int p = blockIdx.x & 3, g = blockIdx.x >> 2;
  const int ubase = g * NUW;
  const float* __restrict__ R = (p & 1) ? Ri : Rr;
  const int kbase = w * 128 + kg * 32;

  // R slice -> registers (one-time, ~17 MB total reads)
  float r[4][32];
#pragma unroll
  for (int kk = 0; kk < 32; ++kk) {
    const float* Rrow = R + (size_t)(kbase + kk) * 2048 + ubase + uu;
#pragma unroll
    for (int gg = 0; gg < 4; ++gg) r[gg][kk] = Rrow[gg * 512];
  }

  __shared__ float zpart[2][256];
  const int myu = p * 512 + ubase + uu;
  float c_old = 0.f;
  if (w == 0 && l < 16) c_old = cs[myu];
  // wave0 lane l computes z column: gate = l>>4, unit = ubase + (l&15)
  const size_t xzrowbase = (size_t)p * chunk * 2048 + (size_t)(ubase + uu) + ((size_t)kg << 9);

  for (int tl = 0; tl < chunk; ++tl) {
    const int t = t0 + tl;
    float xzv = 0.f;
    if (w == 0) xzv = xz[xzrowbase + (size_t)tl * 2048];  // pure input: issue before the poll

    // poll+gather fused: load own 32 pairs, accept when every epoch == t.
    const ull* hp8 = hp + ((t & 1) ? 2048 : 0) + p * 512 + kbase;
    const unsigned tgt = (unsigned)t;
    float hv[32];
    for (;;) {
      ull qv[32];
#pragma unroll
      for (int q = 0; q < 32; ++q)
        qv[q] = __hip_atomic_load(hp8 + q, __ATOMIC_RELAXED, __HIP_MEMORY_SCOPE_AGENT);
      unsigned okm = 1u;
#pragma unroll
      for (int q = 0; q < 32; ++q) {
        okm &= (unsigned)((unsigned)qv[q] == tgt);
        hv[q] = __uint_as_float((unsigned)(qv[q] >> 32));
      }
      if (__all(okm)) break;
    }

    float a[4] = {0.f, 0.f, 0.f, 0.f};
#pragma unroll
    for (int kk = 0; kk < 32; ++kk) {
#pragma unroll
      for (int gg = 0; gg < 4; ++gg) a[gg] = fmaf(r[gg][kk], hv[kk], a[gg]);
    }
    // reduce over the 4 k-groups within the wave (lanes xor 16, 32)
#pragma unroll
    for (int gg = 0; gg < 4; ++gg) {
      a[gg] += __shfl_xor(a[gg], 16);
      a[gg] += __shfl_xor(a[gg], 32);
    }
    if (l < 16) {
#pragma unroll
      for (int gg = 0; gg < 4; ++gg) zpart[t & 1][w * 64 + gg * 16 + l] = a[gg];
    }
    __syncthreads();  // the only barrier: zpart writes -> wave0 read

    if (w == 0) {
      const float* zp = zpart[t & 1];
      float z = zp[l] + zp[64 + l] + zp[128 + l] + zp[192 + l] + xzv;
      float zi = __shfl(z, uu);
      float zf = __shfl(z, uu + 16);
      float zg = __shfl(z, uu + 32);
      float zo = __shfl(z, uu + 48);
      float hn = 0.f, cn = 0.f;
      if (l < 16) {
        cn = sig_f(zf) * c_old + sig_f(zi) * tanh_f(zg);
        hn = sig_f(zo) * tanh_f(cn);
        c_old = cn;
        // publish: ONE 8B atomic store carries data + epoch (t+1), buffer (t+1)&1
        ull pv = ((ull)__float_as_uint(hn) << 32) | (ull)(unsigned)(t + 1);
        __hip_atomic_store(&hp[(((t + 1) & 1) ? 2048 : 0) + p * 512 + ubase + l], pv,
                           __ATOMIC_RELAXED, __HIP_MEMORY_SCOPE_AGENT);
      }
      // out writes after publish: contended cross-XCD atomic acks overlap the
      // next step's poll instead of sitting on the critical path.
      if (l < 16) {
        const size_t oidx = (size_t)t * 512 + ubase + l;
        if (p == 0)      atomicAdd(&out[oidx], hn);                      // real += r2r
        else if (p == 3) atomicAdd(&out[oidx], -hn);                     // real -= i2i
        else             atomicAdd(&out[(size_t)4096000 + oidx], hn);    // imag += r2i/i2r
        if (t == T_TOTAL - 1) {
          out[8192000 + 2 * (size_t)myu + 0] = hn;
          out[8192000 + 2 * (size_t)myu + 1] = cn;
        }
      }
    }
  }
  if (w == 0 && l < 16) cs[myu] = c_old;
}

extern "C" void kernel_launch(void* const* d_in, const int* in_sizes, int n_in,
                              void* d_out, int out_size, void* d_ws, size_t ws_size,
                              hipStream_t stream) {
  (void)in_sizes; (void)n_in;
  const float* in_real   = (const float*)d_in[0];
  const float* in_imag   = (const float*)d_in[1];
  const float* in_states = (const float*)d_in[2];
  const float* Wr = (const float*)d_in[3];
  const float* Rr = (const float*)d_in[4];
  const float* br = (const float*)d_in[5];
  const float* Wi = (const float*)d_in[6];
  const float* Ri = (const float*)d_in[7];
  const float* bi = (const float*)d_in[8];
  float* out = (float*)d_out;

  // ws layout: h pair double-buffer [2][4][512] x 8B (32KB) | c [4][512] (8KB)
  //            | pad to 64KB | xz chunk
  ull* hp = (ull*)d_ws;
  float* cs = (float*)((char*)d_ws + 32768);
  float* xz = (float*)((char*)d_ws + 65536);

  int chunk = 2000;  // halvings all divide 8000
  while (chunk > 125 && (size_t)chunk * 4 * 2048 * sizeof(float) + 65536 > ws_size) chunk >>= 1;

  hipMemsetAsync(d_out, 0, (size_t)out_size * sizeof(float), stream);
  init_kernel<<<2, 1024, 0, stream>>>(in_states, hp, cs);
  for (int t0 = 0; t0 < T_TOTAL; t0 += chunk) {
    dim3 pgrid(2048 / 64, (chunk + 63) / 64, 4);
    proj_kernel<<<pgrid, 256, 0, stream>>>(in_real, in_imag, Wr, br, Wi, bi, xz, t0, chunk);
    recur_kernel<<<4 * GWG, 256, 0, stream>>>(xz, Rr, Ri, hp, cs, out, t0, chunk);
  }
}

// Round 4
// 16040.817 us; speedup vs baseline: 1.4299x; 1.4299x over previous
//
#include <hip/hip_runtime.h>

#define T_TOTAL 8000

typedef unsigned long long ull;

__device__ __forceinline__ float sig_f(float x) { return 1.f / (1.f + __expf(-x)); }
__device__ __forceinline__ float tanh_f(float x) { return 1.f - 2.f / (__expf(2.f * x) + 1.f); }

// ---------------- init: unpack states into epoch-tagged pairs ----------------
// pair: low32 = tag (epoch), high32 = float bits of h. tag e lives in buffer e&1.
// buf0 = (h0, tag 0); buf1 = tag 0 (never matches its first expected tag 1).
__global__ void init_kernel(const float* __restrict__ st, ull* hp, float* cs) {
  int idx = blockIdx.x * blockDim.x + threadIdx.x;
  if (idx < 2048) {  // p*512+u
    unsigned hb = __float_as_uint(st[2 * idx + 0]);
    hp[idx]        = ((ull)hb << 32) | 0ull;
    hp[2048 + idx] = 0ull;               // MUST clear: ws poisoned
    cs[idx] = st[2 * idx + 1];
  }
}

// ---------------- projection: xz[p][t][2048] = x_p @ W_p + b_p ----------------
__global__ __launch_bounds__(256) void proj_kernel(
    const float* __restrict__ in_real, const float* __restrict__ in_imag,
    const float* __restrict__ Wr, const float* __restrict__ br,
    const float* __restrict__ Wi, const float* __restrict__ bi,
    float* __restrict__ xz, int t0, int chunk) {
  const int p = blockIdx.z;
  const float* __restrict__ X = (p < 2) ? in_real : in_imag;
  const float* __restrict__ W = (p & 1) ? Wi : Wr;
  const float* __restrict__ Bv = (p & 1) ? bi : br;
  const int nb = blockIdx.x * 64, mb = blockIdx.y * 64;
  __shared__ float As[16][68];
  __shared__ float Bs[16][68];
  const int tid = threadIdx.x;
  const int tm = tid >> 4, tn = tid & 15;
  const int lam = tid >> 2, lak = (tid & 3) << 2;   // A: row, k-offset
  const int lbk = tid >> 4, lbn = (tid & 15) << 2;  // B: k, col-offset
  float acc[4][4] = {};
  for (int k0 = 0; k0 < 512; k0 += 16) {
    int msafe = mb + lam; if (msafe > chunk - 1) msafe = chunk - 1;
    float4 a4 = *(const float4*)&X[(size_t)(t0 + msafe) * 512 + k0 + lak];
    float4 b4 = *(const float4*)&W[(size_t)(k0 + lbk) * 2048 + nb + lbn];
    __syncthreads();
    As[lak + 0][lam] = a4.x; As[lak + 1][lam] = a4.y;
    As[lak + 2][lam] = a4.z; As[lak + 3][lam] = a4.w;
    *(float4*)&Bs[lbk][lbn] = b4;
    __syncthreads();
#pragma unroll
    for (int k = 0; k < 16; ++k) {
      float4 av = *(const float4*)&As[k][tm << 2];
      float4 bv = *(const float4*)&Bs[k][tn << 2];
      acc[0][0] = fmaf(av.x, bv.x, acc[0][0]); acc[0][1] = fmaf(av.x, bv.y, acc[0][1]);
      acc[0][2] = fmaf(av.x, bv.z, acc[0][2]); acc[0][3] = fmaf(av.x, bv.w, acc[0][3]);
      acc[1][0] = fmaf(av.y, bv.x, acc[1][0]); acc[1][1] = fmaf(av.y, bv.y, acc[1][1]);
      acc[1][2] = fmaf(av.y, bv.z, acc[1][2]); acc[1][3] = fmaf(av.y, bv.w, acc[1][3]);
      acc[2][0] = fmaf(av.z, bv.x, acc[2][0]); acc[2][1] = fmaf(av.z, bv.y, acc[2][1]);
      acc[2][2] = fmaf(av.z, bv.z, acc[2][2]); acc[2][3] = fmaf(av.z, bv.w, acc[2][3]);
      acc[3][0] = fmaf(av.w, bv.x, acc[3][0]); acc[3][1] = fmaf(av.w, bv.y, acc[3][1]);
      acc[3][2] = fmaf(av.w, bv.z, acc[3][2]); acc[3][3] = fmaf(av.w, bv.w, acc[3][3]);
    }
  }
  float4 bias4 = *(const float4*)&Bv[nb + (tn << 2)];
#pragma unroll
  for (int i = 0; i < 4; ++i) {
    int mm = mb + (tm << 2) + i;
    if (mm < chunk) {
      float4 v;
      v.x = acc[i][0] + bias4.x; v.y = acc[i][1] + bias4.y;
      v.z = acc[i][2] + bias4.z; v.w = acc[i][3] + bias4.w;
      *(float4*)&xz[(size_t)(p * chunk + mm) * 2048 + nb + (tn << 2)] = v;
    }
  }
}

// ---------------- persistent recurrent kernel ----------------
// grid = 128 blocks x 256 thr. block: pass p = bx&3, slice g = bx>>2 (16 units).
// wave w owns units U0w..U0w+4 (U0w = g*16+w*4); lane l: unit = l&3, kg = l>>2,
// k-window = kg*32..+32; R slice r[4][32] = 128 regs.
// Step: (a) spin-gather: lane loads pairs {w*128+2l, +2l+1} of buffer t&1 until
//       both tags == t (gather IS the poll; 1KB/wave/retry -- 16x less spin
//       traffic than r3's fused batch, the round-3 regression root cause).
//       (b) stage quarter to padded LDS, lgkm-only barrier (NOT __syncthreads:
//       its vmcnt(0) would drain prior out-atomic acks onto the critical path).
//       (c) FMA from LDS, butterfly reduce (xor 4/8/16/32) -> every lane holds
//       full z for its unit; cell math replicated; owner lanes (l<4) publish
//       one fire-and-forget 8B pair (tag t+1) -- no ack, no flag.
// Safety: WG's 4 waves jointly validate ALL 512 tags t before the barrier and
// publishes happen after it => every WG captured tag t before anyone writes
// t+2 into that buffer (same closure as r3, WG granularity). LDS dbuf by t&1.
__global__ __launch_bounds__(256, 1) void recur_kernel(
    const float* __restrict__ xz, const float* __restrict__ Rr, const float* __restrict__ Ri,
    ull* hp, float* cs, float* out, int t0, int chunk) {
  const int tid = threadIdx.x;
  const int w = tid >> 6, l = tid & 63;
  const int un = l & 3, kg = l >> 2;
  const int p = blockIdx.x & 3, g = blockIdx.x >> 2;
  const int U0w = g * 16 + w * 4;
  const float* __restrict__ R = (p & 1) ? Ri : Rr;

  // R slice -> registers (one-time): r[gate][kk], k = kg*32+kk, col = gate*512 + U0w+un
  float r[4][32];
  {
    const float* Rb = R + (size_t)(kg * 32) * 2048 + (U0w + un);
#pragma unroll
    for (int kk = 0; kk < 32; ++kk) {
#pragma unroll
      for (int gg = 0; gg < 4; ++gg) r[gg][kk] = Rb[(size_t)kk * 2048 + gg * 512];
    }
  }

  // padded LDS h-stage: h[k] at row k>>5, col k&31, stride 36 (2-way bank max)
  __shared__ float hsh[2][16 * 36];
  const int wrow = w * 4 + (l >> 4);          // staging: k = w*128 + 2l
  const int wcol = (2 * l) & 31;
  float c_old = cs[p * 512 + U0w + un];       // replicated across the 16 lanes of a unit

  for (int tl = 0; tl < chunk; ++tl) {
    const int t = t0 + tl;
    // xz prefetch (cached loads; latency hides under the spin)
    float xzv[4];
    {
      const float* xr = xz + ((size_t)p * chunk + tl) * 2048 + (U0w + un);
#pragma unroll
      for (int gg = 0; gg < 4; ++gg) xzv[gg] = xr[gg * 512];
    }

    // (a) spin-gather own 2 pairs of this wave's k-quarter
    const ull* gp = hp + (t & 1) * 2048 + p * 512 + w * 128 + 2 * l;
    const unsigned tgt = (unsigned)t;
    ull q0, q1;
    for (;;) {
      q0 = __hip_atomic_load(gp + 0, __ATOMIC_RELAXED, __HIP_MEMORY_SCOPE_AGENT);
      q1 = __hip_atomic_load(gp + 1, __ATOMIC_RELAXED, __HIP_MEMORY_SCOPE_AGENT);
      if (__all(((unsigned)q0 == tgt) & ((unsigned)q1 == tgt))) break;
    }

    // (b) stage to LDS, lgkm-only barrier
    {
      float2 hv2 = make_float2(__uint_as_float((unsigned)(q0 >> 32)),
                               __uint_as_float((unsigned)(q1 >> 32)));
      *(float2*)&hsh[t & 1][wrow * 36 + wcol] = hv2;
    }
    asm volatile("s_waitcnt lgkmcnt(0)" ::: "memory");
    __builtin_amdgcn_s_barrier();
    asm volatile("" ::: "memory");

    // (c) GEMV from LDS broadcast reads: 8 x float4 of own k-window
    const float* rp = &hsh[t & 1][kg * 36];
    float a[4] = {0.f, 0.f, 0.f, 0.f};
#pragma unroll
    for (int q = 0; q < 8; ++q) {
      float4 h4 = *(const float4*)(rp + 4 * q);
#pragma unroll
      for (int gg = 0; gg < 4; ++gg) {
        a[gg] = fmaf(r[gg][4 * q + 0], h4.x, a[gg]);
        a[gg] = fmaf(r[gg][4 * q + 1], h4.y, a[gg]);
        a[gg] = fmaf(r[gg][4 * q + 2], h4.z, a[gg]);
        a[gg] = fmaf(r[gg][4 * q + 3], h4.w, a[gg]);
      }
    }
    // butterfly over the 16 lanes of this unit (lane bits 2..5)
#pragma unroll
    for (int gg = 0; gg < 4; ++gg) {
      a[gg] += __shfl_xor(a[gg], 4);
      a[gg] += __shfl_xor(a[gg], 8);
      a[gg] += __shfl_xor(a[gg], 16);
      a[gg] += __shfl_xor(a[gg], 32);
    }
    const float zi = a[0] + xzv[0], zf = a[1] + xzv[1];
    const float zg = a[2] + xzv[2], zo = a[3] + xzv[3];
    const float cn = sig_f(zf) * c_old + sig_f(zi) * tanh_f(zg);
    const float hn = sig_f(zo) * tanh_f(cn);
    c_old = cn;  // identical across the unit's 16 lanes

    // publish (owners, fire-and-forget), then out atomics off the critical path
    if (l < 4) {
      ull pv = ((ull)__float_as_uint(hn) << 32) | (ull)(unsigned)(t + 1);
      __hip_atomic_store(&hp[((t + 1) & 1) * 2048 + p * 512 + U0w + l], pv,
                         __ATOMIC_RELAXED, __HIP_MEMORY_SCOPE_AGENT);
      const size_t oidx = (size_t)t * 512 + U0w + l;
      if (p == 0)      atomicAdd(&out[oidx], hn);                    // real += r2r
      else if (p == 3) atomicAdd(&out[oidx], -hn);                   // real -= i2i
      else             atomicAdd(&out[(size_t)4096000 + oidx], hn);  // imag += r2i/i2r
      if (t == T_TOTAL - 1) {
        const size_t myu = (size_t)p * 512 + U0w + l;
        out[8192000 + 2 * myu + 0] = hn;
        out[8192000 + 2 * myu + 1] = cn;
      }
    }
  }
  if (l < 4) cs[p * 512 + U0w + l] = c_old;
}

extern "C" void kernel_launch(void* const* d_in, const int* in_sizes, int n_in,
                              void* d_out, int out_size, void* d_ws, size_t ws_size,
                              hipStream_t stream) {
  (void)in_sizes; (void)n_in;
  const float* in_real   = (const float*)d_in[0];
  const float* in_imag   = (const float*)d_in[1];
  const float* in_states = (const float*)d_in[2];
  const float* Wr = (const float*)d_in[3];
  const float* Rr = (const float*)d_in[4];
  const float* br = (const float*)d_in[5];
  const float* Wi = (const float*)d_in[6];
  const float* Ri = (const float*)d_in[7];
  const float* bi = (const float*)d_in[8];
  float* out = (float*)d_out;

  // ws layout: h pair double-buffer [2][4][512] x 8B (32KB) | c [4][512] (8KB)
  //            | pad to 64KB | xz chunk
  ull* hp = (ull*)d_ws;
  float* cs = (float*)((char*)d_ws + 32768);
  float* xz = (float*)((char*)d_ws + 65536);

  int chunk = 2000;  // halvings all divide 8000
  while (chunk > 125 && (size_t)chunk * 4 * 2048 * sizeof(float) + 65536 > ws_size) chunk >>= 1;

  hipMemsetAsync(d_out, 0, (size_t)out_size * sizeof(float), stream);
  init_kernel<<<2, 1024, 0, stream>>>(in_states, hp, cs);
  for (int t0 = 0; t0 < T_TOTAL; t0 += chunk) {
    dim3 pgrid(2048 / 64, (chunk + 63) / 64, 4);
    proj_kernel<<<pgrid, 256, 0, stream>>>(in_real, in_imag, Wr, br, Wi, bi, xz, t0, chunk);
    recur_kernel<<<128, 256, 0, stream>>>(xz, Rr, Ri, hp, cs, out, t0, chunk);
  }
}